// Round 10
// baseline (544.013 us; speedup 1.0000x reference)
//
#include <hip/hip_runtime.h>
#include <cstdint>
#include <cstddef>

#define Tt 2048
#define Hh 1024
#define Ff 3584
#define Ee 8
#define ROWS_CAP 5120

#define OFF_CTRL   0u
#define OFF_TOKE   4096u
#define OFF_TOKW   (4096u + 16384u)
#define OFF_ROWMAP 65536u
#define OFF_ROWW   98304u
#define OFF_XG     (1ull << 20)
#define OFF_G      (12ull << 20)

typedef __attribute__((ext_vector_type(8))) short bf16x8;
typedef __attribute__((ext_vector_type(4))) float f32x4;

__device__ __forceinline__ unsigned short f2bf(float f) {
  unsigned int u = __float_as_uint(f);
  u += 0x7fffu + ((u >> 16) & 1u);
  return (unsigned short)(u >> 16);
}

__device__ __forceinline__ unsigned pkbf(float a, float b) {
  unsigned r;
  asm("v_cvt_pk_bf16_f32 %0, %1, %2" : "=v"(r) : "v"(a), "v"(b));
  return r;
}

__device__ __forceinline__ void gload_lds16(const void* g, void* l) {
  auto gp = (const __attribute__((address_space(1))) char*)(uintptr_t)g;
  auto lp = (__attribute__((address_space(3))) char*)(uintptr_t)l;
  __builtin_amdgcn_global_load_lds(gp, lp, 16, 0, 0);
}

// LDS tile: rows x 32k bf16 (64 B/row); chunk gc at pos = gc ^ ((row>>1)&3).
__device__ __forceinline__ bf16x8 frg(const char* lds, int row, int gc) {
  return *(const bf16x8*)(lds + row * 64 + ((gc ^ ((row >> 1) & 3)) * 16));
}

// ---------------- router ----------------
__global__ __launch_bounds__(256) void router_kernel(
    const float* __restrict__ x, const float* __restrict__ gw,
    float* __restrict__ logits_out, int* __restrict__ tok_e,
    float* __restrict__ tok_w, int* __restrict__ ctrl) {
  const int lane = threadIdx.x & 63;
  const int t = blockIdx.x * 4 + (threadIdx.x >> 6);
  const float4* xp = (const float4*)(x + (size_t)t * Hh + lane * 16);
  float4 x0 = xp[0], x1 = xp[1], x2 = xp[2], x3 = xp[3];
  float lg[Ee];
#pragma unroll
  for (int e = 0; e < Ee; ++e) {
    const float4* gp = (const float4*)(gw + e * Hh + lane * 16);
    float4 g0 = gp[0], g1 = gp[1], g2 = gp[2], g3 = gp[3];
    float s = x0.x*g0.x + x0.y*g0.y + x0.z*g0.z + x0.w*g0.w
            + x1.x*g1.x + x1.y*g1.y + x1.z*g1.z + x1.w*g1.w
            + x2.x*g2.x + x2.y*g2.y + x2.z*g2.z + x2.w*g2.w
            + x3.x*g3.x + x3.y*g3.y + x3.z*g3.z + x3.w*g3.w;
#pragma unroll
    for (int o = 32; o; o >>= 1) s += __shfl_xor(s, o);
    lg[e] = s;
  }
  if (lane == 0) {
    float m = lg[0];
#pragma unroll
    for (int e = 1; e < Ee; ++e) m = fmaxf(m, lg[e]);
    float p[Ee];
#pragma unroll
    for (int e = 0; e < Ee; ++e) p[e] = expf(lg[e] - m);
    int a0 = 0;
#pragma unroll
    for (int e = 1; e < Ee; ++e) if (p[e] > p[a0]) a0 = e;
    int a1 = (a0 == 0) ? 1 : 0;
#pragma unroll
    for (int e = 0; e < Ee; ++e) if (e != a0 && p[e] > p[a1]) a1 = e;
    float rs = p[a0] + p[a1];
    float w0 = p[a0] / rs, w1 = p[a1] / rs;
#pragma unroll
    for (int e = 0; e < Ee; ++e) logits_out[(size_t)t * Ee + e] = lg[e];
    tok_e[t * 2] = a0; tok_e[t * 2 + 1] = a1;
    tok_w[t * 2] = w0; tok_w[t * 2 + 1] = w1;
    atomicAdd(&ctrl[a0], 1); atomicAdd(&ctrl[a1], 1);
  }
}

__global__ void offsets_kernel(int* ctrl) {
  if (threadIdx.x == 0) {
    int acc = 0;
    for (int e = 0; e < Ee; ++e) {
      ctrl[16 + e] = acc;
      acc += ((ctrl[e] + 127) >> 7) << 7;   // pad to 128
    }
    ctrl[16 + Ee] = acc;
  }
}

__global__ __launch_bounds__(512) void assign_kernel(
    int* ctrl, const int* __restrict__ tok_e, const float* __restrict__ tok_w,
    int* __restrict__ rowmap, float* __restrict__ roww) {
  int i = blockIdx.x * 512 + threadIdx.x;
  if (i < 2 * Tt) {
    int e = tok_e[i];
    int pos = atomicAdd(&ctrl[8 + e], 1);
    int r = ctrl[16 + e] + pos;
    rowmap[r] = i >> 1;
    roww[r] = tok_w[i];
  }
  if (i < Ee * 128) {
    int e = i >> 7, pd = i & 127;
    int o = ctrl[16 + e], o1 = ctrl[16 + e + 1], c = ctrl[e];
    int r = o + c + pd;
    if (r < o1) { rowmap[r] = -1; roww[r] = 0.f; }
  }
}

// ---------------- gather x rows -> bf16 Xg ----------------
__global__ __launch_bounds__(128) void gather_kernel(
    const float* __restrict__ x, const int* __restrict__ ctrl,
    const int* __restrict__ rowmap, unsigned short* __restrict__ Xg) {
  int r = blockIdx.x;
  if (r >= ctrl[16 + Ee]) return;
  int t = rowmap[r];
  int j = threadIdx.x;
  uint4 v = make_uint4(0u, 0u, 0u, 0u);
  if (t >= 0) {
    const float4* xp = (const float4*)(x + (size_t)t * Hh + j * 8);
    float4 a = xp[0], b = xp[1];
    v.x = (unsigned)f2bf(a.x) | ((unsigned)f2bf(a.y) << 16);
    v.y = (unsigned)f2bf(a.z) | ((unsigned)f2bf(a.w) << 16);
    v.z = (unsigned)f2bf(b.x) | ((unsigned)f2bf(b.y) << 16);
    v.w = (unsigned)f2bf(b.z) | ((unsigned)f2bf(b.w) << 16);
  }
  *(uint4*)(Xg + (size_t)r * Hh + j * 8) = v;
}

// ---------- ffn13: G = silu(Xg@w1^T)*(Xg@w3^T), 128x128, BK=32, 512 thr ----------
// Triple-buffer d=3: iter it computes tile it (staged at it-2), stages tile it+2,
// issues B(it+4) reg loads. Barrier wait drains ONLY ops issued one full iter ago.
// vmcnt ledger (17 ops/iter = 1 glds + 16 B-dwords): steady in-flight at barrier =
// [A(it+1), B(it+3)x16, A(it+2), B(it+4)x16] = 34 -> drain 17 -> vmcnt(17).
// Tails (issue guards stop): it==28,29 -> vmcnt(1); it==30 -> vmcnt(0); it==31 none.
__global__ __launch_bounds__(512, 4) void ffn13_fused(
    const unsigned short* __restrict__ Xg, const float* __restrict__ w1,
    const float* __restrict__ w3, const int* __restrict__ ctrl,
    unsigned short* __restrict__ G) {
  __shared__ alignas(16) char bA[3][8192], bB1[3][8192], bB3[3][8192];
  int lin = blockIdx.y * 28 + blockIdx.x;          // 0..3583
  int xcd = lin & 7, idx = lin >> 3;
  int p = xcd + 8 * (idx >> 4);                    // panel pinned to XCD
  int mt = idx & 15;
  int e = p / 28, bx = p % 28;
  const int off0 = ctrl[16 + e], off1 = ctrl[16 + e + 1];
  const int row0 = off0 + mt * 128;
  if (row0 >= off1) return;
  const int n0 = bx * 128;
  const int tid = threadIdx.x, lane = tid & 63, wv = tid >> 6;
  const int wr = wv >> 2, wc = wv & 3;             // wave tile 64x32
  const float* w1e = w1 + (size_t)e * Hh * Ff;
  const float* w3e = w3 + (size_t)e * Hh * Ff;
  f32x4 acc1[4][2] = {};
  f32x4 acc3[4][2] = {};
  const int srow = wv * 16 + (lane >> 2);
  const int sgc = (lane & 3) ^ ((lane >> 3) & 3);
  const unsigned short* gA = Xg + (size_t)(row0 + srow) * Hh + sgc * 8;
  const int bn = tid & 127, bkq = tid >> 7;
  const int wofB = bn * 64 + ((bkq ^ ((bn >> 1) & 3)) * 16);
  const float* pB1 = w1e + (size_t)(bkq * 8) * Ff + n0 + bn;
  const float* pB3 = w3e + (size_t)(bkq * 8) * Ff + n0 + bn;
  float r1e[8], r3e[8], r1o[8], r3o[8];

  char *cA = bA[0], *nA = bA[1], *xA = bA[2];
  char *cB1 = bB1[0], *nB1 = bB1[1], *xB1 = bB1[2];
  char *cB3 = bB3[0], *nB3 = bB3[1], *xB3 = bB3[2];

  // ---- prologue: preload B(0)->e, B(1)->o; stage(0)->c; stage(1)->n; hard drain ----
#pragma unroll
  for (int i = 0; i < 8; ++i) { r1e[i] = pB1[(size_t)i * Ff]; r3e[i] = pB3[(size_t)i * Ff]; }
#pragma unroll
  for (int i = 0; i < 8; ++i) { r1o[i] = pB1[(size_t)(32 + i) * Ff]; r3o[i] = pB3[(size_t)(32 + i) * Ff]; }
  gload_lds16(gA, cA + wv * 1024);
  __builtin_amdgcn_sched_barrier(0);
  {
    uint4 q;
    q.x = pkbf(r1e[0], r1e[1]); q.y = pkbf(r1e[2], r1e[3]);
    q.z = pkbf(r1e[4], r1e[5]); q.w = pkbf(r1e[6], r1e[7]);
    *(uint4*)(cB1 + wofB) = q;
    q.x = pkbf(r3e[0], r3e[1]); q.y = pkbf(r3e[2], r3e[3]);
    q.z = pkbf(r3e[4], r3e[5]); q.w = pkbf(r3e[6], r3e[7]);
    *(uint4*)(cB3 + wofB) = q;
  }
#pragma unroll
  for (int i = 0; i < 8; ++i) { r1e[i] = pB1[(size_t)(64 + i) * Ff]; r3e[i] = pB3[(size_t)(64 + i) * Ff]; }
  gload_lds16(gA + 32, nA + wv * 1024);
  __builtin_amdgcn_sched_barrier(0);
  {
    uint4 q;
    q.x = pkbf(r1o[0], r1o[1]); q.y = pkbf(r1o[2], r1o[3]);
    q.z = pkbf(r1o[4], r1o[5]); q.w = pkbf(r1o[6], r1o[7]);
    *(uint4*)(nB1 + wofB) = q;
    q.x = pkbf(r3o[0], r3o[1]); q.y = pkbf(r3o[2], r3o[3]);
    q.z = pkbf(r3o[4], r3o[5]); q.w = pkbf(r3o[6], r3o[7]);
    *(uint4*)(nB3 + wofB) = q;
  }
#pragma unroll
  for (int i = 0; i < 8; ++i) { r1o[i] = pB1[(size_t)(96 + i) * Ff]; r3o[i] = pB3[(size_t)(96 + i) * Ff]; }
  asm volatile("s_waitcnt vmcnt(0) lgkmcnt(0)" ::: "memory");
  __builtin_amdgcn_s_barrier();
  __builtin_amdgcn_sched_barrier(0);

#define H13_STEP(IT, R1, R3)                                                   \
  {                                                                            \
    if ((IT) < 30) gload_lds16(gA + (size_t)((IT) + 2) * 32, xA + wv * 1024);  \
    __builtin_amdgcn_sched_barrier(0);                                         \
    if ((IT) < 30) {                                                           \
      uint4 q;                                                                 \
      q.x = pkbf(R1[0], R1[1]); q.y = pkbf(R1[2], R1[3]);                      \
      q.z = pkbf(R1[4], R1[5]); q.w = pkbf(R1[6], R1[7]);                      \
      *(uint4*)(xB1 + wofB) = q;                                               \
      q.x = pkbf(R3[0], R3[1]); q.y = pkbf(R3[2], R3[3]);                      \
      q.z = pkbf(R3[4], R3[5]); q.w = pkbf(R3[6], R3[7]);                      \
      *(uint4*)(xB3 + wofB) = q;                                               \
    }                                                                          \
    if ((IT) < 28) {                                                           \
      const float* p1 = pB1 + (size_t)((IT) + 4) * 32 * Ff;                    \
      const float* p3 = pB3 + (size_t)((IT) + 4) * 32 * Ff;                    \
      _Pragma("unroll") for (int i = 0; i < 8; ++i) {                          \
        R1[i] = p1[(size_t)i * Ff]; R3[i] = p3[(size_t)i * Ff]; }              \
    }                                                                          \
    __builtin_amdgcn_sched_barrier(0);                                         \
    { const int gc = lane >> 4;                                                \
      bf16x8 af[4];                                                            \
      _Pragma("unroll") for (int mi = 0; mi < 4; ++mi)                         \
        af[mi] = frg(cA, wr * 64 + mi * 16 + (lane & 15), gc);                 \
      __builtin_amdgcn_s_setprio(1);                                           \
      _Pragma("unroll") for (int ni = 0; ni < 2; ++ni) {                       \
        bf16x8 b1 = frg(cB1, wc * 32 + ni * 16 + (lane & 15), gc);             \
        bf16x8 b3 = frg(cB3, wc * 32 + ni * 16 + (lane & 15), gc);             \
        _Pragma("unroll") for (int mi = 0; mi < 4; ++mi) {                     \
          acc1[mi][ni] = __builtin_amdgcn_mfma_f32_16x16x32_bf16(af[mi], b1, acc1[mi][ni], 0, 0, 0); \
          acc3[mi][ni] = __builtin_amdgcn_mfma_f32_16x16x32_bf16(af[mi], b3, acc3[mi][ni], 0, 0, 0); \
        }                                                                      \
      }                                                                        \
      __builtin_amdgcn_s_setprio(0); }                                         \
    if ((IT) < 31) {                                                           \
      if ((IT) < 28)      asm volatile("s_waitcnt vmcnt(17) lgkmcnt(0)" ::: "memory"); \
      else if ((IT) < 30) asm volatile("s_waitcnt vmcnt(1) lgkmcnt(0)" ::: "memory");  \
      else                asm volatile("s_waitcnt vmcnt(0) lgkmcnt(0)" ::: "memory");  \
      __builtin_amdgcn_s_barrier();                                            \
      __builtin_amdgcn_sched_barrier(0);                                       \
    }                                                                          \
    { char* t_ = cA; cA = nA; nA = xA; xA = t_;                                \
      t_ = cB1; cB1 = nB1; nB1 = xB1; xB1 = t_;                                \
      t_ = cB3; cB3 = nB3; nB3 = xB3; xB3 = t_; }                              \
  }

  for (int j = 0; j < 16; ++j) {
    H13_STEP(2 * j, r1e, r3e)
    H13_STEP(2 * j + 1, r1o, r3o)
  }
#undef H13_STEP

  const int rb = wr * 64 + 4 * (lane >> 4), cb = wc * 32 + (lane & 15);
#pragma unroll
  for (int mi = 0; mi < 4; ++mi)
#pragma unroll
    for (int ni = 0; ni < 2; ++ni)
#pragma unroll
      for (int r = 0; r < 4; ++r) {
        float h1 = acc1[mi][ni][r], h3 = acc3[mi][ni][r];
        float gv = h1 / (1.f + __expf(-h1)) * h3;
        G[(size_t)(row0 + rb + mi * 16 + r) * Ff + n0 + cb + ni * 16] = f2bf(gv);
      }
}

// ---------- ffn2: out[t] += w * (G@w2^T), 128x128, BK=32, K-split x2, d=3 ----------
// 9 ops/iter (1 glds + 8 B-dwords): steady vmcnt(9); tails: it==52,53 ->1; 54 ->0.
__global__ __launch_bounds__(512, 4) void ffn2_fused(
    const unsigned short* __restrict__ G, const float* __restrict__ w2,
    const int* __restrict__ ctrl, const int* __restrict__ rowmap,
    const float* __restrict__ roww, float* __restrict__ out) {
  __shared__ alignas(16) char bA[3][8192], bB[3][8192];
  int lin = (blockIdx.z * 128 + blockIdx.y) * 8 + blockIdx.x;  // 0..2047
  int xcd = lin & 7, idx = lin >> 3;
  int e = idx >> 5, sub = idx & 31;
  int mt = sub >> 1, ks = sub & 1;
  int bx = xcd;
  const int off0 = ctrl[16 + e], off1 = ctrl[16 + e + 1];
  const int row0 = off0 + mt * 128;
  if (row0 >= off1) return;
  const int n0 = bx * 128;
  const int kb = ks * (Ff / 2);
  const int tid = threadIdx.x, lane = tid & 63, wv = tid >> 6;
  const int wr = wv >> 2, wc = wv & 3;             // wave tile 64x32
  const float* w2e = w2 + (size_t)e * Ff * Hh;
  f32x4 acc[4][2] = {};
  const int srow = wv * 16 + (lane >> 2);
  const int sgc = (lane & 3) ^ ((lane >> 3) & 3);
  const unsigned short* gA = G + (size_t)(row0 + srow) * Ff + kb + sgc * 8;
  const int bn = tid & 127, bkq = tid >> 7;
  const int wofB = bn * 64 + ((bkq ^ ((bn >> 1) & 3)) * 16);
  const float* pB = w2e + (size_t)(kb + bkq * 8) * Hh + n0 + bn;
  float rbe[8], rbo[8];

  char *cA = bA[0], *nA = bA[1], *xA = bA[2];
  char *cB = bB[0], *nB = bB[1], *xB = bB[2];

  // ---- prologue ----
#pragma unroll
  for (int i = 0; i < 8; ++i) rbe[i] = pB[(size_t)i * Hh];
#pragma unroll
  for (int i = 0; i < 8; ++i) rbo[i] = pB[(size_t)(32 + i) * Hh];
  gload_lds16(gA, cA + wv * 1024);
  __builtin_amdgcn_sched_barrier(0);
  {
    uint4 q;
    q.x = pkbf(rbe[0], rbe[1]); q.y = pkbf(rbe[2], rbe[3]);
    q.z = pkbf(rbe[4], rbe[5]); q.w = pkbf(rbe[6], rbe[7]);
    *(uint4*)(cB + wofB) = q;
  }
#pragma unroll
  for (int i = 0; i < 8; ++i) rbe[i] = pB[(size_t)(64 + i) * Hh];
  gload_lds16(gA + 32, nA + wv * 1024);
  __builtin_amdgcn_sched_barrier(0);
  {
    uint4 q;
    q.x = pkbf(rbo[0], rbo[1]); q.y = pkbf(rbo[2], rbo[3]);
    q.z = pkbf(rbo[4], rbo[5]); q.w = pkbf(rbo[6], rbo[7]);
    *(uint4*)(nB + wofB) = q;
  }
#pragma unroll
  for (int i = 0; i < 8; ++i) rbo[i] = pB[(size_t)(96 + i) * Hh];
  asm volatile("s_waitcnt vmcnt(0) lgkmcnt(0)" ::: "memory");
  __builtin_amdgcn_s_barrier();
  __builtin_amdgcn_sched_barrier(0);

#define F2_STEP(IT, BS)                                                        \
  {                                                                            \
    if ((IT) < 54) gload_lds16(gA + (size_t)((IT) + 2) * 32, xA + wv * 1024);  \
    __builtin_amdgcn_sched_barrier(0);                                         \
    if ((IT) < 54) {                                                           \
      uint4 q;                                                                 \
      q.x = pkbf(BS[0], BS[1]); q.y = pkbf(BS[2], BS[3]);                      \
      q.z = pkbf(BS[4], BS[5]); q.w = pkbf(BS[6], BS[7]);                      \
      *(uint4*)(xB + wofB) = q;                                                \
    }                                                                          \
    if ((IT) < 52) {                                                           \
      const float* pw = pB + (size_t)((IT) + 4) * 32 * Hh;                     \
      _Pragma("unroll") for (int i = 0; i < 8; ++i) BS[i] = pw[(size_t)i * Hh];\
    }                                                                          \
    __builtin_amdgcn_sched_barrier(0);                                         \
    { const int gc = lane >> 4;                                                \
      bf16x8 af[4];                                                            \
      _Pragma("unroll") for (int mi = 0; mi < 4; ++mi)                         \
        af[mi] = frg(cA, wr * 64 + mi * 16 + (lane & 15), gc);                 \
      __builtin_amdgcn_s_setprio(1);                                           \
      _Pragma("unroll") for (int ni = 0; ni < 2; ++ni) {                       \
        bf16x8 b = frg(cB, wc * 32 + ni * 16 + (lane & 15), gc);               \
        _Pragma("unroll") for (int mi = 0; mi < 4; ++mi)                       \
          acc[mi][ni] = __builtin_amdgcn_mfma_f32_16x16x32_bf16(af[mi], b, acc[mi][ni], 0, 0, 0); \
      }                                                                        \
      __builtin_amdgcn_s_setprio(0); }                                         \
    if ((IT) < 55) {                                                           \
      if ((IT) < 52)      asm volatile("s_waitcnt vmcnt(9) lgkmcnt(0)" ::: "memory"); \
      else if ((IT) < 54) asm volatile("s_waitcnt vmcnt(1) lgkmcnt(0)" ::: "memory"); \
      else                asm volatile("s_waitcnt vmcnt(0) lgkmcnt(0)" ::: "memory"); \
      __builtin_amdgcn_s_barrier();                                            \
      __builtin_amdgcn_sched_barrier(0);                                       \
    }                                                                          \
    { char* t_ = cA; cA = nA; nA = xA; xA = t_;                                \
      t_ = cB; cB = nB; nB = xB; xB = t_; }                                    \
  }

  for (int j = 0; j < 28; ++j) {
    F2_STEP(2 * j, rbe)
    F2_STEP(2 * j + 1, rbo)
  }
#undef F2_STEP

  const int rb = wr * 64 + 4 * (lane >> 4), cb = wc * 32 + (lane & 15);
#pragma unroll
  for (int mi = 0; mi < 4; ++mi)
#pragma unroll
    for (int r = 0; r < 4; ++r) {
      int grow = row0 + rb + mi * 16 + r;
      int t = rowmap[grow];
      if (t < 0) continue;
      float wgt = roww[grow];
#pragma unroll
      for (int ni = 0; ni < 2; ++ni)
        atomicAdd(&out[(size_t)t * Hh + n0 + cb + ni * 16], wgt * acc[mi][ni][r]);
    }
}

extern "C" void kernel_launch(void* const* d_in, const int* in_sizes, int n_in,
                              void* d_out, int out_size, void* d_ws, size_t ws_size,
                              hipStream_t stream) {
  const float* x  = (const float*)d_in[0];
  const float* gw = (const float*)d_in[1];
  const float* w1 = (const float*)d_in[2];
  const float* w3 = (const float*)d_in[3];
  const float* w2 = (const float*)d_in[4];
  float* out = (float*)d_out;
  float* logits = out + (size_t)Tt * Hh;
  char* ws = (char*)d_ws;
  int* ctrl = (int*)(ws + OFF_CTRL);
  int* tok_e = (int*)(ws + OFF_TOKE);
  float* tok_w = (float*)(ws + OFF_TOKW);
  int* rowmap = (int*)(ws + OFF_ROWMAP);
  float* roww = (float*)(ws + OFF_ROWW);
  unsigned short* Xg = (unsigned short*)(ws + OFF_XG);
  unsigned short* G  = (unsigned short*)(ws + OFF_G);

  hipMemsetAsync(ctrl, 0, 256, stream);
  hipMemsetAsync(out, 0, (size_t)Tt * Hh * sizeof(float), stream);
  router_kernel<<<Tt / 4, 256, 0, stream>>>(x, gw, logits, tok_e, tok_w, ctrl);
  offsets_kernel<<<1, 64, 0, stream>>>(ctrl);
  assign_kernel<<<8, 512, 0, stream>>>(ctrl, tok_e, tok_w, rowmap, roww);
  gather_kernel<<<ROWS_CAP, 128, 0, stream>>>(x, ctrl, rowmap, Xg);
  ffn13_fused<<<dim3(28, 128), 512, 0, stream>>>(Xg, w1, w3, ctrl, G);
  ffn2_fused<<<dim3(8, 128, 2), 512, 0, stream>>>(G, w2, ctrl, rowmap, roww, out);
}

// Round 11
// 349.334 us; speedup vs baseline: 1.5573x; 1.5573x over previous
//
#include <hip/hip_runtime.h>
#include <cstdint>
#include <cstddef>

#define Tt 2048
#define Hh 1024
#define Ff 3584
#define Ee 8
#define ROWS_CAP 5120
#define MAXT 40   // max flat m-tiles: sum ceil(c_e/128) <= 32+8

#define OFF_CTRL   0u
#define OFF_TOKE   4096u
#define OFF_TOKW   (4096u + 16384u)
#define OFF_ROWMAP 65536u
#define OFF_ROWW   98304u
#define OFF_XG     (1ull << 20)
#define OFF_G      (12ull << 20)

typedef __attribute__((ext_vector_type(8))) short bf16x8;
typedef __attribute__((ext_vector_type(4))) float f32x4;

__device__ __forceinline__ unsigned short f2bf(float f) {
  unsigned int u = __float_as_uint(f);
  u += 0x7fffu + ((u >> 16) & 1u);
  return (unsigned short)(u >> 16);
}

__device__ __forceinline__ unsigned pkbf(float a, float b) {
  unsigned r;
  asm("v_cvt_pk_bf16_f32 %0, %1, %2" : "=v"(r) : "v"(a), "v"(b));
  return r;
}

__device__ __forceinline__ void gload_lds16(const void* g, void* l) {
  auto gp = (const __attribute__((address_space(1))) char*)(uintptr_t)g;
  auto lp = (__attribute__((address_space(3))) char*)(uintptr_t)l;
  __builtin_amdgcn_global_load_lds(gp, lp, 16, 0, 0);
}

// LDS tile: rows x 32k bf16 (64 B/row); chunk gc at pos = gc ^ ((row>>1)&3).
__device__ __forceinline__ bf16x8 frg(const char* lds, int row, int gc) {
  return *(const bf16x8*)(lds + row * 64 + ((gc ^ ((row >> 1) & 3)) * 16));
}

// ---------------- router ----------------
__global__ __launch_bounds__(256) void router_kernel(
    const float* __restrict__ x, const float* __restrict__ gw,
    float* __restrict__ logits_out, int* __restrict__ tok_e,
    float* __restrict__ tok_w, int* __restrict__ ctrl) {
  const int lane = threadIdx.x & 63;
  const int t = blockIdx.x * 4 + (threadIdx.x >> 6);
  const float4* xp = (const float4*)(x + (size_t)t * Hh + lane * 16);
  float4 x0 = xp[0], x1 = xp[1], x2 = xp[2], x3 = xp[3];
  float lg[Ee];
#pragma unroll
  for (int e = 0; e < Ee; ++e) {
    const float4* gp = (const float4*)(gw + e * Hh + lane * 16);
    float4 g0 = gp[0], g1 = gp[1], g2 = gp[2], g3 = gp[3];
    float s = x0.x*g0.x + x0.y*g0.y + x0.z*g0.z + x0.w*g0.w
            + x1.x*g1.x + x1.y*g1.y + x1.z*g1.z + x1.w*g1.w
            + x2.x*g2.x + x2.y*g2.y + x2.z*g2.z + x2.w*g2.w
            + x3.x*g3.x + x3.y*g3.y + x3.z*g3.z + x3.w*g3.w;
#pragma unroll
    for (int o = 32; o; o >>= 1) s += __shfl_xor(s, o);
    lg[e] = s;
  }
  if (lane == 0) {
    float m = lg[0];
#pragma unroll
    for (int e = 1; e < Ee; ++e) m = fmaxf(m, lg[e]);
    float p[Ee];
#pragma unroll
    for (int e = 0; e < Ee; ++e) p[e] = expf(lg[e] - m);
    int a0 = 0;
#pragma unroll
    for (int e = 1; e < Ee; ++e) if (p[e] > p[a0]) a0 = e;
    int a1 = (a0 == 0) ? 1 : 0;
#pragma unroll
    for (int e = 0; e < Ee; ++e) if (e != a0 && p[e] > p[a1]) a1 = e;
    float rs = p[a0] + p[a1];
    float w0 = p[a0] / rs, w1 = p[a1] / rs;
#pragma unroll
    for (int e = 0; e < Ee; ++e) logits_out[(size_t)t * Ee + e] = lg[e];
    tok_e[t * 2] = a0; tok_e[t * 2 + 1] = a1;
    tok_w[t * 2] = w0; tok_w[t * 2 + 1] = w1;
    atomicAdd(&ctrl[a0], 1); atomicAdd(&ctrl[a1], 1);
  }
}

// offsets + flat m-tile table: ctrl[32+2*i]=e, ctrl[33+2*i]=row0 (-1 = dead)
__global__ void offsets_kernel(int* ctrl) {
  if (threadIdx.x == 0) {
    int acc = 0;
    for (int e = 0; e < Ee; ++e) {
      ctrl[16 + e] = acc;
      acc += ((ctrl[e] + 127) >> 7) << 7;
    }
    ctrl[16 + Ee] = acc;
    int idx = 0;
    for (int e = 0; e < Ee; ++e) {
      int nt = (ctrl[e] + 127) >> 7;
      for (int m = 0; m < nt && idx < MAXT; ++m) {
        ctrl[32 + 2 * idx] = e;
        ctrl[33 + 2 * idx] = ctrl[16 + e] + m * 128;
        ++idx;
      }
    }
    for (; idx < MAXT; ++idx) { ctrl[32 + 2 * idx] = 0; ctrl[33 + 2 * idx] = -1; }
  }
}

__global__ __launch_bounds__(512) void assign_kernel(
    int* ctrl, const int* __restrict__ tok_e, const float* __restrict__ tok_w,
    int* __restrict__ rowmap, float* __restrict__ roww) {
  int i = blockIdx.x * 512 + threadIdx.x;
  if (i < 2 * Tt) {
    int e = tok_e[i];
    int pos = atomicAdd(&ctrl[8 + e], 1);
    int r = ctrl[16 + e] + pos;
    rowmap[r] = i >> 1;
    roww[r] = tok_w[i];
  }
  if (i < Ee * 128) {
    int e = i >> 7, pd = i & 127;
    int o = ctrl[16 + e], o1 = ctrl[16 + e + 1], c = ctrl[e];
    int r = o + c + pd;
    if (r < o1) { rowmap[r] = -1; roww[r] = 0.f; }
  }
}

// ---------------- gather x rows -> bf16 Xg ----------------
__global__ __launch_bounds__(128) void gather_kernel(
    const float* __restrict__ x, const int* __restrict__ ctrl,
    const int* __restrict__ rowmap, unsigned short* __restrict__ Xg) {
  int r = blockIdx.x;
  if (r >= ctrl[16 + Ee]) return;
  int t = rowmap[r];
  int j = threadIdx.x;
  uint4 v = make_uint4(0u, 0u, 0u, 0u);
  if (t >= 0) {
    const float4* xp = (const float4*)(x + (size_t)t * Hh + j * 8);
    float4 a = xp[0], b = xp[1];
    v.x = (unsigned)f2bf(a.x) | ((unsigned)f2bf(a.y) << 16);
    v.y = (unsigned)f2bf(a.z) | ((unsigned)f2bf(a.w) << 16);
    v.z = (unsigned)f2bf(b.x) | ((unsigned)f2bf(b.y) << 16);
    v.w = (unsigned)f2bf(b.z) | ((unsigned)f2bf(b.w) << 16);
  }
  *(uint4*)(Xg + (size_t)r * Hh + j * 8) = v;
}

// ---------- ffn13: G = silu(Xg@w1^T)*(Xg@w3^T), 128x128, BK=32, 512 thr ----------
// R6-proven d=2 pipeline, compacted grid: x=28 n-tiles, y=MAXT flat m-tiles.
// vmcnt ledger at barrier: [A(it+1), B(it+2)x16] = 17 -> vmcnt(16) drains A(it+1).
// Tail it==30: no B issued -> vmcnt(0).
__global__ __launch_bounds__(512, 4) void ffn13_fused(
    const unsigned short* __restrict__ Xg, const float* __restrict__ w1,
    const float* __restrict__ w3, const int* __restrict__ ctrl,
    unsigned short* __restrict__ G) {
  __shared__ alignas(16) char sA[2][8192], sB1[2][8192], sB3[2][8192];
  int lin = blockIdx.y * 28 + blockIdx.x;          // 0..1119 = 8*140
  int wg = (lin & 7) * 140 + (lin >> 3);           // chunked bijective XCD swizzle
  int bx = wg % 28, ft = wg / 28;
  const int e = ctrl[32 + 2 * ft];
  const int row0 = ctrl[33 + 2 * ft];
  if (row0 < 0) return;
  const int n0 = bx * 128;
  const int tid = threadIdx.x, lane = tid & 63, wv = tid >> 6;
  const int wr = wv >> 2, wc = wv & 3;             // wave tile 64x32
  const float* w1e = w1 + (size_t)e * Hh * Ff;
  const float* w3e = w3 + (size_t)e * Hh * Ff;
  f32x4 acc1[4][2] = {};
  f32x4 acc3[4][2] = {};
  const int srow = wv * 16 + (lane >> 2);
  const int sgc = (lane & 3) ^ ((lane >> 3) & 3);
  const unsigned short* gA = Xg + (size_t)(row0 + srow) * Hh + sgc * 8;
  const int bn = tid & 127, bkq = tid >> 7;
  const int wofB = bn * 64 + ((bkq ^ ((bn >> 1) & 3)) * 16);
  const float* pB1 = w1e + (size_t)(bkq * 8) * Ff + n0 + bn;
  const float* pB3 = w3e + (size_t)(bkq * 8) * Ff + n0 + bn;
  float r1[8], r3[8];

  // ---- prologue: A(0)->sA[0]; B(0)->regs->sB[0]; B(1)->regs; HARD drain ----
  gload_lds16(gA, sA[0] + wv * 1024);
  __builtin_amdgcn_sched_barrier(0);
#pragma unroll
  for (int i = 0; i < 8; ++i) r1[i] = pB1[(size_t)i * Ff];
#pragma unroll
  for (int i = 0; i < 8; ++i) r3[i] = pB3[(size_t)i * Ff];
  {
    uint4 q;
    q.x = pkbf(r1[0], r1[1]); q.y = pkbf(r1[2], r1[3]);
    q.z = pkbf(r1[4], r1[5]); q.w = pkbf(r1[6], r1[7]);
    *(uint4*)(sB1[0] + wofB) = q;
    q.x = pkbf(r3[0], r3[1]); q.y = pkbf(r3[2], r3[3]);
    q.z = pkbf(r3[4], r3[5]); q.w = pkbf(r3[6], r3[7]);
    *(uint4*)(sB3[0] + wofB) = q;
  }
#pragma unroll
  for (int i = 0; i < 8; ++i) r1[i] = pB1[(size_t)(32 + i) * Ff];
#pragma unroll
  for (int i = 0; i < 8; ++i) r3[i] = pB3[(size_t)(32 + i) * Ff];
  asm volatile("s_waitcnt vmcnt(0) lgkmcnt(0)" ::: "memory");
  __builtin_amdgcn_s_barrier();
  __builtin_amdgcn_sched_barrier(0);

  for (int it = 0; it < 32; ++it) {
    const int cur = it & 1;
    if (it < 31) gload_lds16(gA + (size_t)(it + 1) * 32, sA[cur ^ 1] + wv * 1024);
    __builtin_amdgcn_sched_barrier(0);
    if (it < 31) {
      uint4 q;
      q.x = pkbf(r1[0], r1[1]); q.y = pkbf(r1[2], r1[3]);
      q.z = pkbf(r1[4], r1[5]); q.w = pkbf(r1[6], r1[7]);
      *(uint4*)(sB1[cur ^ 1] + wofB) = q;
      q.x = pkbf(r3[0], r3[1]); q.y = pkbf(r3[2], r3[3]);
      q.z = pkbf(r3[4], r3[5]); q.w = pkbf(r3[6], r3[7]);
      *(uint4*)(sB3[cur ^ 1] + wofB) = q;
    }
    if (it < 30) {
      const float* p1 = pB1 + (size_t)(it + 2) * 32 * Ff;
      const float* p3 = pB3 + (size_t)(it + 2) * 32 * Ff;
#pragma unroll
      for (int i = 0; i < 8; ++i) r1[i] = p1[(size_t)i * Ff];
#pragma unroll
      for (int i = 0; i < 8; ++i) r3[i] = p3[(size_t)i * Ff];
    }
    __builtin_amdgcn_sched_barrier(0);
    {
      const int gc = lane >> 4;
      bf16x8 af[4];
#pragma unroll
      for (int mi = 0; mi < 4; ++mi)
        af[mi] = frg(sA[cur], wr * 64 + mi * 16 + (lane & 15), gc);
      __builtin_amdgcn_s_setprio(1);
#pragma unroll
      for (int ni = 0; ni < 2; ++ni) {
        bf16x8 b1 = frg(sB1[cur], wc * 32 + ni * 16 + (lane & 15), gc);
        bf16x8 b3 = frg(sB3[cur], wc * 32 + ni * 16 + (lane & 15), gc);
#pragma unroll
        for (int mi = 0; mi < 4; ++mi) {
          acc1[mi][ni] = __builtin_amdgcn_mfma_f32_16x16x32_bf16(af[mi], b1, acc1[mi][ni], 0, 0, 0);
          acc3[mi][ni] = __builtin_amdgcn_mfma_f32_16x16x32_bf16(af[mi], b3, acc3[mi][ni], 0, 0, 0);
        }
      }
      __builtin_amdgcn_s_setprio(0);
    }
    if (it < 31) {
      if (it < 30) asm volatile("s_waitcnt vmcnt(16) lgkmcnt(0)" ::: "memory");
      else         asm volatile("s_waitcnt vmcnt(0) lgkmcnt(0)" ::: "memory");
      __builtin_amdgcn_s_barrier();
      __builtin_amdgcn_sched_barrier(0);
    }
  }
  const int rb = wr * 64 + 4 * (lane >> 4), cb = wc * 32 + (lane & 15);
#pragma unroll
  for (int mi = 0; mi < 4; ++mi)
#pragma unroll
    for (int ni = 0; ni < 2; ++ni)
#pragma unroll
      for (int r = 0; r < 4; ++r) {
        float h1 = acc1[mi][ni][r], h3 = acc3[mi][ni][r];
        float gv = h1 / (1.f + __expf(-h1)) * h3;
        G[(size_t)(row0 + rb + mi * 16 + r) * Ff + n0 + cb + ni * 16] = f2bf(gv);
      }
}

// ---------- ffn2: out[t] += w * (G@w2^T), 128x128, BK=32, K-split x2 ----------
// R6-proven d=2 pipeline, compacted grid: x=8 n-tiles, y=MAXT, z=2 ksplit.
// Ledger: [A(it+1), B(it+2)x8] = 9 -> vmcnt(8); tail it==54 -> vmcnt(0).
__global__ __launch_bounds__(512, 4) void ffn2_fused(
    const unsigned short* __restrict__ G, const float* __restrict__ w2,
    const int* __restrict__ ctrl, const int* __restrict__ rowmap,
    const float* __restrict__ roww, float* __restrict__ out) {
  __shared__ alignas(16) char sA[2][8192], sB[2][8192];
  int lin = (blockIdx.z * MAXT + blockIdx.y) * 8 + blockIdx.x;  // 0..639 = 8*80
  int wg = (lin & 7) * 80 + (lin >> 3);
  int bx = wg & 7, t2 = wg >> 3;                   // t2 0..79
  int ft = t2 % MAXT, ks = t2 / MAXT;
  const int e = ctrl[32 + 2 * ft];
  const int row0 = ctrl[33 + 2 * ft];
  if (row0 < 0) return;
  const int n0 = bx * 128;
  const int kb = ks * (Ff / 2);
  const int tid = threadIdx.x, lane = tid & 63, wv = tid >> 6;
  const int wr = wv >> 2, wc = wv & 3;             // wave tile 64x32
  const float* w2e = w2 + (size_t)e * Ff * Hh;
  f32x4 acc[4][2] = {};
  const int srow = wv * 16 + (lane >> 2);
  const int sgc = (lane & 3) ^ ((lane >> 3) & 3);
  const unsigned short* gA = G + (size_t)(row0 + srow) * Ff + kb + sgc * 8;
  const int bn = tid & 127, bkq = tid >> 7;
  const int wofB = bn * 64 + ((bkq ^ ((bn >> 1) & 3)) * 16);
  const float* pB = w2e + (size_t)(kb + bkq * 8) * Hh + n0 + bn;
  float r2[8];

  // ---- prologue ----
  gload_lds16(gA, sA[0] + wv * 1024);
  __builtin_amdgcn_sched_barrier(0);
#pragma unroll
  for (int i = 0; i < 8; ++i) r2[i] = pB[(size_t)i * Hh];
  {
    uint4 q;
    q.x = pkbf(r2[0], r2[1]); q.y = pkbf(r2[2], r2[3]);
    q.z = pkbf(r2[4], r2[5]); q.w = pkbf(r2[6], r2[7]);
    *(uint4*)(sB[0] + wofB) = q;
  }
#pragma unroll
  for (int i = 0; i < 8; ++i) r2[i] = pB[(size_t)(32 + i) * Hh];
  asm volatile("s_waitcnt vmcnt(0) lgkmcnt(0)" ::: "memory");
  __builtin_amdgcn_s_barrier();
  __builtin_amdgcn_sched_barrier(0);

  const int NT = 56;
  for (int it = 0; it < NT; ++it) {
    const int cur = it & 1;
    if (it < NT - 1) gload_lds16(gA + (size_t)(it + 1) * 32, sA[cur ^ 1] + wv * 1024);
    __builtin_amdgcn_sched_barrier(0);
    if (it < NT - 1) {
      uint4 q;
      q.x = pkbf(r2[0], r2[1]); q.y = pkbf(r2[2], r2[3]);
      q.z = pkbf(r2[4], r2[5]); q.w = pkbf(r2[6], r2[7]);
      *(uint4*)(sB[cur ^ 1] + wofB) = q;
    }
    if (it < NT - 2) {
      const float* pw = pB + (size_t)(it + 2) * 32 * Hh;
#pragma unroll
      for (int i = 0; i < 8; ++i) r2[i] = pw[(size_t)i * Hh];
    }
    __builtin_amdgcn_sched_barrier(0);
    {
      const int gc = lane >> 4;
      bf16x8 af[4];
#pragma unroll
      for (int mi = 0; mi < 4; ++mi)
        af[mi] = frg(sA[cur], wr * 64 + mi * 16 + (lane & 15), gc);
      __builtin_amdgcn_s_setprio(1);
#pragma unroll
      for (int ni = 0; ni < 2; ++ni) {
        bf16x8 b = frg(sB[cur], wc * 32 + ni * 16 + (lane & 15), gc);
#pragma unroll
        for (int mi = 0; mi < 4; ++mi)
          acc[mi][ni] = __builtin_amdgcn_mfma_f32_16x16x32_bf16(af[mi], b, acc[mi][ni], 0, 0, 0);
      }
      __builtin_amdgcn_s_setprio(0);
    }
    if (it < NT - 1) {
      if (it < NT - 2) asm volatile("s_waitcnt vmcnt(8) lgkmcnt(0)" ::: "memory");
      else             asm volatile("s_waitcnt vmcnt(0) lgkmcnt(0)" ::: "memory");
      __builtin_amdgcn_s_barrier();
      __builtin_amdgcn_sched_barrier(0);
    }
  }
  const int rb = wr * 64 + 4 * (lane >> 4), cb = wc * 32 + (lane & 15);
#pragma unroll
  for (int mi = 0; mi < 4; ++mi)
#pragma unroll
    for (int r = 0; r < 4; ++r) {
      int grow = row0 + rb + mi * 16 + r;
      int t = rowmap[grow];
      if (t < 0) continue;
      float wgt = roww[grow];
#pragma unroll
      for (int ni = 0; ni < 2; ++ni)
        atomicAdd(&out[(size_t)t * Hh + n0 + cb + ni * 16], wgt * acc[mi][ni][r]);
    }
}

extern "C" void kernel_launch(void* const* d_in, const int* in_sizes, int n_in,
                              void* d_out, int out_size, void* d_ws, size_t ws_size,
                              hipStream_t stream) {
  const float* x  = (const float*)d_in[0];
  const float* gw = (const float*)d_in[1];
  const float* w1 = (const float*)d_in[2];
  const float* w3 = (const float*)d_in[3];
  const float* w2 = (const float*)d_in[4];
  float* out = (float*)d_out;
  float* logits = out + (size_t)Tt * Hh;
  char* ws = (char*)d_ws;
  int* ctrl = (int*)(ws + OFF_CTRL);
  int* tok_e = (int*)(ws + OFF_TOKE);
  float* tok_w = (float*)(ws + OFF_TOKW);
  int* rowmap = (int*)(ws + OFF_ROWMAP);
  float* roww = (float*)(ws + OFF_ROWW);
  unsigned short* Xg = (unsigned short*)(ws + OFF_XG);
  unsigned short* G  = (unsigned short*)(ws + OFF_G);

  hipMemsetAsync(ctrl, 0, 512, stream);
  hipMemsetAsync(out, 0, (size_t)Tt * Hh * sizeof(float), stream);
  router_kernel<<<Tt / 4, 256, 0, stream>>>(x, gw, logits, tok_e, tok_w, ctrl);
  offsets_kernel<<<1, 64, 0, stream>>>(ctrl);
  assign_kernel<<<8, 512, 0, stream>>>(ctrl, tok_e, tok_w, rowmap, roww);
  gather_kernel<<<ROWS_CAP, 128, 0, stream>>>(x, ctrl, rowmap, Xg);
  ffn13_fused<<<dim3(28, MAXT), 512, 0, stream>>>(Xg, w1, w3, ctrl, G);
  ffn2_fused<<<dim3(8, MAXT, 2), 512, 0, stream>>>(G, w2, ctrl, rowmap, roww, out);
}